// Round 9
// baseline (19752.861 us; speedup 1.0000x reference)
//
#include <hip/hip_runtime.h>
#include <hip/hip_bf16.h>
#include <stdint.h>

#define D_MODEL 2048
#define NHEADS 16
#define NKV 4
#define HD 128
#define BATCH 2
#define SEQ 2048
#define NTOK (BATCH*SEQ)
#define QKV_N 3072
#define QSCALE 0.08838834764831845f

// ---- naive fp32 GEMM, B in natural [K][N] layout (no transpose anywhere) ----
// C[m*ldc + c0 + n] = sum_k A[m][k] * B[k][n]
__global__ __launch_bounds__(256) void gemm_nn_f32(const float* __restrict__ A,
                                                   const float* __restrict__ B,
                                                   float* __restrict__ C,
                                                   int M, int N, int K, int ldc, int c0) {
    size_t i = (size_t)blockIdx.x * 256 + threadIdx.x;
    if (i >= (size_t)M * N) return;
    int m = (int)(i / N), n = (int)(i % N);
    const float* a = A + (size_t)m * K;
    const float* b = B + n;
    float acc = 0.f;
    for (int k = 0; k < K; ++k)
        acc += a[k] * b[(size_t)k * N];
    C[(size_t)m * ldc + c0 + n] = acc;
}

// ---- RoPE on fp32 qkv (cols 0..2559), double-precision trig, NO q scale ----
__global__ __launch_bounds__(256) void rope_f32(float* __restrict__ qkv) {
    int idx = blockIdx.x * 256 + threadIdx.x;   // < 4096*1280
    int token = idx / 1280;
    int pc = idx - token * 1280;
    int head = pc >> 6;     // 0..19 (0-15 q heads, 16-19 k heads)
    int i = pc & 63;
    int col = head * 128 + 2 * i;               // q: 0..2047, k: 2048..2559
    int s = token & (SEQ - 1);
    double inv_freq = pow(10000.0, -(double)i / 64.0);
    double ang = (double)s * inv_freq;
    double sn_d, cs_d;
    sincos(ang, &sn_d, &cs_d);
    float cs = (float)cs_d, sn = (float)sn_d;
    size_t base = (size_t)token * QKV_N + col;
    float e0 = qkv[base];
    float e1 = qkv[base + 1];
    qkv[base]     = e0 * cs - e1 * sn;
    qkv[base + 1] = e1 * cs + e0 * sn;
}

// ---- fp32 scalar attention: 1 wave per (b,h,s); scale applied to scores like ref ----
__global__ __launch_bounds__(64) void attn_f32(const float* __restrict__ qkv,
                                               float* __restrict__ y) {
    const int s = blockIdx.x, h = blockIdx.y, b = blockIdx.z;
    const int kvh = h >> 2, lane = threadIdx.x;

    const float2 qp = *((const float2*)(qkv + (size_t)(b * SEQ + s) * QKV_N + h * HD) + lane);

    const float2* kbase =
        (const float2*)(qkv + (size_t)(b * SEQ) * QKV_N + D_MODEL + kvh * HD) + lane;
    // row stride in float2 units: 3072/2 = 1536; v is +512 floats = +256 float2
    float m = -3.0e38f, l = 0.f, a0 = 0.f, a1 = 0.f;

    for (int k = 0; k <= s; ++k) {
        float2 kb = kbase[(size_t)k * 1536];
        float t = qp.x * kb.x + qp.y * kb.y;
#pragma unroll
        for (int o = 1; o < 64; o <<= 1) t += __shfl_xor(t, o);
        t *= QSCALE;                                   // scale scores (ref order)
        float mn = fmaxf(m, t);
        float al = __expf(m - mn);
        float p  = __expf(t - mn);
        float2 vb = kbase[(size_t)k * 1536 + 256];
        l = l * al + p;
        m = mn;
        a0 = a0 * al + p * vb.x;
        a1 = a1 * al + p * vb.y;
    }
    float2* yp = (float2*)(y + (size_t)(b * SEQ + s) * D_MODEL + h * HD) + lane;
    *yp = make_float2(a0 / l, a1 / l);
}

extern "C" void kernel_launch(void* const* d_in, const int* in_sizes, int n_in,
                              void* d_out, int out_size, void* d_ws, size_t ws_size,
                              hipStream_t stream) {
    const float* x  = (const float*)d_in[0];
    const float* wq = (const float*)d_in[1];
    const float* wk = (const float*)d_in[2];
    const float* wv = (const float*)d_in[3];
    const float* wo = (const float*)d_in[4];

    // Layout (all fp32):
    //   ws:    qkv [4096][3072] @ W[0 .. 50.33MB)   (phases 1-3)
    //          outf [4096][2048] @ W[0 .. 33.55MB)  (phase 4; qkv dead)
    //   d_out: yb  [4096][2048] scratch (phase 3); final result after memcpy
    float* qkv  = (float*)d_ws;
    float* outf = (float*)d_ws;
    float* yb   = (float*)d_out;

    // phase 1: QKV projections straight from fp32 inputs (B in natural layout)
    gemm_nn_f32<<<dim3((int)(((size_t)NTOK * 2048 + 255) / 256)), 256, 0, stream>>>(
        x, wq, qkv, NTOK, 2048, D_MODEL, QKV_N, 0);
    gemm_nn_f32<<<dim3((int)(((size_t)NTOK * 512 + 255) / 256)), 256, 0, stream>>>(
        x, wk, qkv, NTOK, 512, D_MODEL, QKV_N, 2048);
    gemm_nn_f32<<<dim3((int)(((size_t)NTOK * 512 + 255) / 256)), 256, 0, stream>>>(
        x, wv, qkv, NTOK, 512, D_MODEL, QKV_N, 2560);

    // phase 2: RoPE (double trig)
    rope_f32<<<dim3(NTOK * 1280 / 256), 256, 0, stream>>>(qkv);

    // phase 3: attention -> yb (d_out scratch)
    attn_f32<<<dim3(SEQ, NHEADS, BATCH), 64, 0, stream>>>(qkv, yb);

    // phase 4: output projection -> ws staging (qkv dead), then D2D to d_out
    gemm_nn_f32<<<dim3((int)(((size_t)NTOK * 2048 + 255) / 256)), 256, 0, stream>>>(
        yb, wo, outf, NTOK, D_MODEL, D_MODEL, D_MODEL, 0);
    hipMemcpyAsync(d_out, outf, (size_t)NTOK * D_MODEL * sizeof(float),
                   hipMemcpyDeviceToDevice, stream);
}

// Round 10
// 4824.157 us; speedup vs baseline: 4.0946x; 4.0946x over previous
//
#include <hip/hip_runtime.h>
#include <hip/hip_bf16.h>
#include <stdint.h>

typedef __hip_bfloat16 bf16;
typedef __attribute__((ext_vector_type(8))) short short8;
typedef __attribute__((ext_vector_type(4))) float f32x4;

#define D_MODEL 2048
#define NHEADS 16
#define NKV 4
#define HD 128
#define BATCH 2
#define SEQ 2048
#define NTOK (BATCH*SEQ)
#define QKV_N 3072
#define QSCALE 0.08838834764831845f

// ---------------- naive convert: fp32 -> bf16, 1 thread/element ----------------
__global__ __launch_bounds__(256) void conv_naive(const float* __restrict__ in,
                                                  bf16* __restrict__ out, size_t n) {
    size_t i = (size_t)blockIdx.x * 256 + threadIdx.x;
    if (i < n) out[i] = __float2bfloat16(in[i]);
}

// ------- naive convert-transpose: in fp32 [K][N] -> out bf16 [N][K], 1 thread/element -------
__global__ __launch_bounds__(256) void ct_naive(const float* __restrict__ in,
                                                bf16* __restrict__ out, int K, int N) {
    size_t i = (size_t)blockIdx.x * 256 + threadIdx.x;
    if (i >= (size_t)K * N) return;
    int k = (int)(i / N), n = (int)(i % N);
    out[(size_t)n * K + k] = __float2bfloat16(in[i]);
}

// ------------- GEMM: C[M][N] = A[M][K] * Bt[N][K]^T (m97 structure), OutT store -------------
template <typename OutT>
__global__ __launch_bounds__(256) void gemm_bt(const bf16* __restrict__ A,
                                               const bf16* __restrict__ Bt,
                                               OutT* __restrict__ C, int M, int N, int K) {
    __shared__ bf16 As[128 * 32];
    __shared__ bf16 Bs[128 * 32];
    const int m0 = blockIdx.y * 128, n0 = blockIdx.x * 128;
    const int tid = threadIdx.x;
    const int wave = tid >> 6, lane = tid & 63;
    const int wr = wave >> 1, wc = wave & 1;
    const int l15 = lane & 15, g = lane >> 4;
    const int srow = lane >> 2;
    const int sk8 = (lane & 3) * 8;
    f32x4 acc[4][4] = {};

    for (int k0 = 0; k0 < K; k0 += 32) {
        __syncthreads();
#pragma unroll
        for (int i = 0; i < 2; ++i) {
            int chunk = wave * 2 + i;
            const bf16* ga = A + (size_t)(m0 + chunk * 16 + srow) * K + k0 + sk8;
            bf16* la = As + chunk * 512 + lane * 8;
            __builtin_amdgcn_global_load_lds((const __attribute__((address_space(1))) void*)ga,
                                             (__attribute__((address_space(3))) void*)la, 16, 0, 0);
            const bf16* gb = Bt + (size_t)(n0 + chunk * 16 + srow) * K + k0 + sk8;
            bf16* lb = Bs + chunk * 512 + lane * 8;
            __builtin_amdgcn_global_load_lds((const __attribute__((address_space(1))) void*)gb,
                                             (__attribute__((address_space(3))) void*)lb, 16, 0, 0);
        }
        __syncthreads();
        short8 af[4], bfr[4];
#pragma unroll
        for (int mi = 0; mi < 4; ++mi)
            af[mi] = *(const short8*)&As[(wr * 64 + mi * 16 + l15) * 32 + g * 8];
#pragma unroll
        for (int ni = 0; ni < 4; ++ni)
            bfr[ni] = *(const short8*)&Bs[(wc * 64 + ni * 16 + l15) * 32 + g * 8];
#pragma unroll
        for (int mi = 0; mi < 4; ++mi)
#pragma unroll
            for (int ni = 0; ni < 4; ++ni)
                acc[mi][ni] = __builtin_amdgcn_mfma_f32_16x16x32_bf16(af[mi], bfr[ni], acc[mi][ni], 0, 0, 0);
    }
#pragma unroll
    for (int mi = 0; mi < 4; ++mi)
#pragma unroll
        for (int ni = 0; ni < 4; ++ni) {
            int row = m0 + wr * 64 + mi * 16 + g * 4;
            int col = n0 + wc * 64 + ni * 16 + l15;
#pragma unroll
            for (int r = 0; r < 4; ++r) {
                float v = acc[mi][ni][r];
                if constexpr (__is_same(OutT, float))
                    C[(size_t)(row + r) * N + col] = v;
                else
                    C[(size_t)(row + r) * N + col] = __float2bfloat16(v);
            }
        }
}

// ---- RoPE on fp32 qkv (cols 0..2559), double-precision trig, NO q scale (R9, passing) ----
__global__ __launch_bounds__(256) void rope_f32(float* __restrict__ qkv) {
    int idx = blockIdx.x * 256 + threadIdx.x;   // < 4096*1280
    int token = idx / 1280;
    int pc = idx - token * 1280;
    int head = pc >> 6;     // 0..19 (0-15 q heads, 16-19 k heads)
    int i = pc & 63;
    int col = head * 128 + 2 * i;               // q: 0..2047, k: 2048..2559
    int s = token & (SEQ - 1);
    double inv_freq = pow(10000.0, -(double)i / 64.0);
    double ang = (double)s * inv_freq;
    double sn_d, cs_d;
    sincos(ang, &sn_d, &cs_d);
    float cs = (float)cs_d, sn = (float)sn_d;
    size_t base = (size_t)token * QKV_N + col;
    float e0 = qkv[base];
    float e1 = qkv[base + 1];
    qkv[base]     = e0 * cs - e1 * sn;
    qkv[base + 1] = e1 * cs + e0 * sn;
}

// ---- fp32 scalar attention (R9, passing): 1 wave per (b,h,s); scores scaled like ref ----
__global__ __launch_bounds__(64) void attn_f32(const float* __restrict__ qkv,
                                               float* __restrict__ y) {
    const int s = blockIdx.x, h = blockIdx.y, b = blockIdx.z;
    const int kvh = h >> 2, lane = threadIdx.x;

    const float2 qp = *((const float2*)(qkv + (size_t)(b * SEQ + s) * QKV_N + h * HD) + lane);

    const float2* kbase =
        (const float2*)(qkv + (size_t)(b * SEQ) * QKV_N + D_MODEL + kvh * HD) + lane;
    float m = -3.0e38f, l = 0.f, a0 = 0.f, a1 = 0.f;

    for (int k = 0; k <= s; ++k) {
        float2 kb = kbase[(size_t)k * 1536];
        float t = qp.x * kb.x + qp.y * kb.y;
#pragma unroll
        for (int o = 1; o < 64; o <<= 1) t += __shfl_xor(t, o);
        t *= QSCALE;
        float mn = fmaxf(m, t);
        float al = __expf(m - mn);
        float p  = __expf(t - mn);
        float2 vb = kbase[(size_t)k * 1536 + 256];
        l = l * al + p;
        m = mn;
        a0 = a0 * al + p * vb.x;
        a1 = a1 * al + p * vb.y;
    }
    float2* yp = (float2*)(y + (size_t)(b * SEQ + s) * D_MODEL + h * HD) + lane;
    *yp = make_float2(a0 / l, a1 / l);
}

extern "C" void kernel_launch(void* const* d_in, const int* in_sizes, int n_in,
                              void* d_out, int out_size, void* d_ws, size_t ws_size,
                              hipStream_t stream) {
    const float* x  = (const float*)d_in[0];
    const float* wq = (const float*)d_in[1];
    const float* wk = (const float*)d_in[2];
    const float* wv = (const float*)d_in[3];
    const float* wo = (const float*)d_in[4];

    // Layout:
    //   ws    (≥50.33MB proven): qkv_f32 [4096][3072] @ W[0..50.33MB)  (phases 1-3)
    //         phase 4 (qkv dead): ybb bf16 [4096][2048] @ W[0..16.78MB),
    //                              woT bf16 [2048][2048] @ W[16.78..25.17MB)
    //   d_out (33.55MB): phase 1: xb bf16 @ O[0..8.39M el), wqkvT bf16 @ O[8.39M..14.68M el)
    //                    phase 3: yb fp32 scratch (xb/wqkvT dead)
    //                    phase 4: final fp32 output (yb dead after conversion)
    float* qkv  = (float*)d_ws;
    bf16*  ybb  = (bf16*)d_ws;
    bf16*  woT  = (bf16*)d_ws + (size_t)NTOK * D_MODEL;
    bf16*  xb    = (bf16*)d_out;
    bf16*  wqkvT = (bf16*)d_out + (size_t)NTOK * D_MODEL;
    float* yb   = (float*)d_out;
    float* outf = (float*)d_out;

    // phase 1: converts into d_out scratch (naive, audited)
    conv_naive<<<dim3((NTOK * D_MODEL + 255) / 256), 256, 0, stream>>>(x, xb, (size_t)NTOK * D_MODEL);
    ct_naive<<<dim3((2048 * 2048 + 255) / 256), 256, 0, stream>>>(wq, wqkvT, 2048, 2048);
    ct_naive<<<dim3((2048 * 512 + 255) / 256), 256, 0, stream>>>(wk, wqkvT + (size_t)2048 * 2048, 2048, 512);
    ct_naive<<<dim3((2048 * 512 + 255) / 256), 256, 0, stream>>>(wv, wqkvT + (size_t)2560 * 2048, 2048, 512);

    // phase 2: fused QKV projection via MFMA (bf16 in, fp32 out) + RoPE (fp32)
    gemm_bt<float><<<dim3(QKV_N / 128, NTOK / 128), 256, 0, stream>>>(xb, wqkvT, qkv, NTOK, QKV_N, D_MODEL);
    rope_f32<<<dim3(NTOK * 1280 / 256), 256, 0, stream>>>(qkv);

    // phase 3: attention fp32 (reads ws qkv, writes d_out yb; xb/wqkvT dead)
    attn_f32<<<dim3(SEQ, NHEADS, BATCH), 64, 0, stream>>>(qkv, yb);

    // phase 4: convert yb->bf16 into ws (qkv dead), wo^T -> bf16 ws, MFMA out-proj -> d_out
    conv_naive<<<dim3((NTOK * D_MODEL + 255) / 256), 256, 0, stream>>>(yb, ybb, (size_t)NTOK * D_MODEL);
    ct_naive<<<dim3((2048 * 2048 + 255) / 256), 256, 0, stream>>>(wo, woT, 2048, 2048);
    gemm_bt<float><<<dim3(D_MODEL / 128, NTOK / 128), 256, 0, stream>>>(ybb, woT, outf, NTOK, D_MODEL, D_MODEL);
}

// Round 11
// 688.518 us; speedup vs baseline: 28.6889x; 7.0066x over previous
//
#include <hip/hip_runtime.h>
#include <hip/hip_bf16.h>
#include <stdint.h>

typedef __hip_bfloat16 bf16;
typedef __attribute__((ext_vector_type(8))) short short8;
typedef __attribute__((ext_vector_type(4))) float f32x4;

#define D_MODEL 2048
#define NHEADS 16
#define NKV 4
#define HD 128
#define BATCH 2
#define SEQ 2048
#define NTOK (BATCH*SEQ)
#define QKV_N 3072
#define QSCALE 0.08838834764831845f

// ---------------- naive convert: fp32 -> bf16, 1 thread/element ----------------
__global__ __launch_bounds__(256) void conv_naive(const float* __restrict__ in,
                                                  bf16* __restrict__ out, size_t n) {
    size_t i = (size_t)blockIdx.x * 256 + threadIdx.x;
    if (i < n) out[i] = __float2bfloat16(in[i]);
}

// ------- naive convert-transpose: in fp32 [K][N] -> out bf16 [N][K], 1 thread/element -------
__global__ __launch_bounds__(256) void ct_naive(const float* __restrict__ in,
                                                bf16* __restrict__ out, int K, int N) {
    size_t i = (size_t)blockIdx.x * 256 + threadIdx.x;
    if (i >= (size_t)K * N) return;
    int k = (int)(i / N), n = (int)(i % N);
    out[(size_t)n * K + k] = __float2bfloat16(in[i]);
}

// ------------- GEMM: C[M][N] = A[M][K] * Bt[N][K]^T (m97 structure), OutT store -------------
template <typename OutT>
__global__ __launch_bounds__(256) void gemm_bt(const bf16* __restrict__ A,
                                               const bf16* __restrict__ Bt,
                                               OutT* __restrict__ C, int M, int N, int K) {
    __shared__ bf16 As[128 * 32];
    __shared__ bf16 Bs[128 * 32];
    const int m0 = blockIdx.y * 128, n0 = blockIdx.x * 128;
    const int tid = threadIdx.x;
    const int wave = tid >> 6, lane = tid & 63;
    const int wr = wave >> 1, wc = wave & 1;
    const int l15 = lane & 15, g = lane >> 4;
    const int srow = lane >> 2;
    const int sk8 = (lane & 3) * 8;
    f32x4 acc[4][4] = {};

    for (int k0 = 0; k0 < K; k0 += 32) {
        __syncthreads();
#pragma unroll
        for (int i = 0; i < 2; ++i) {
            int chunk = wave * 2 + i;
            const bf16* ga = A + (size_t)(m0 + chunk * 16 + srow) * K + k0 + sk8;
            bf16* la = As + chunk * 512 + lane * 8;
            __builtin_amdgcn_global_load_lds((const __attribute__((address_space(1))) void*)ga,
                                             (__attribute__((address_space(3))) void*)la, 16, 0, 0);
            const bf16* gb = Bt + (size_t)(n0 + chunk * 16 + srow) * K + k0 + sk8;
            bf16* lb = Bs + chunk * 512 + lane * 8;
            __builtin_amdgcn_global_load_lds((const __attribute__((address_space(1))) void*)gb,
                                             (__attribute__((address_space(3))) void*)lb, 16, 0, 0);
        }
        __syncthreads();
        short8 af[4], bfr[4];
#pragma unroll
        for (int mi = 0; mi < 4; ++mi)
            af[mi] = *(const short8*)&As[(wr * 64 + mi * 16 + l15) * 32 + g * 8];
#pragma unroll
        for (int ni = 0; ni < 4; ++ni)
            bfr[ni] = *(const short8*)&Bs[(wc * 64 + ni * 16 + l15) * 32 + g * 8];
#pragma unroll
        for (int mi = 0; mi < 4; ++mi)
#pragma unroll
            for (int ni = 0; ni < 4; ++ni)
                acc[mi][ni] = __builtin_amdgcn_mfma_f32_16x16x32_bf16(af[mi], bfr[ni], acc[mi][ni], 0, 0, 0);
    }
#pragma unroll
    for (int mi = 0; mi < 4; ++mi)
#pragma unroll
        for (int ni = 0; ni < 4; ++ni) {
            int row = m0 + wr * 64 + mi * 16 + g * 4;
            int col = n0 + wc * 64 + ni * 16 + l15;
#pragma unroll
            for (int r = 0; r < 4; ++r) {
                float v = acc[mi][ni][r];
                if constexpr (__is_same(OutT, float))
                    C[(size_t)(row + r) * N + col] = v;
                else
                    C[(size_t)(row + r) * N + col] = __float2bfloat16(v);
            }
        }
}

// ---- RoPE on fp32 qkv (cols 0..2559), double trig, no q scale (R9/R10, passing) ----
__global__ __launch_bounds__(256) void rope_f32(float* __restrict__ qkv) {
    int idx = blockIdx.x * 256 + threadIdx.x;   // < 4096*1280
    int token = idx / 1280;
    int pc = idx - token * 1280;
    int head = pc >> 6;
    int i = pc & 63;
    int col = head * 128 + 2 * i;
    int s = token & (SEQ - 1);
    double inv_freq = pow(10000.0, -(double)i / 64.0);
    double ang = (double)s * inv_freq;
    double sn_d, cs_d;
    sincos(ang, &sn_d, &cs_d);
    float cs = (float)cs_d, sn = (float)sn_d;
    size_t base = (size_t)token * QKV_N + col;
    float e0 = qkv[base];
    float e1 = qkv[base + 1];
    qkv[base]     = e0 * cs - e1 * sn;
    qkv[base + 1] = e1 * cs + e0 * sn;
}

// ------- MFMA flash attention reading fp32 qkv; bf16 fragments in-kernel -------
// grid (SEQ/64, NHEADS, BATCH), 256 thr. Scores scaled by QSCALE in fp32 (R9 semantics).
#define KS_LD 136   // 272B row stride, 16B-aligned short8 rows
#define VT_LD 40    // 80B row stride
__device__ __forceinline__ short8 cvt8(const float* p) {
    union { short8 v; bf16 e[8]; } u;
#pragma unroll
    for (int j = 0; j < 8; ++j) u.e[j] = __float2bfloat16(p[j]);
    return u.v;
}
__global__ __launch_bounds__(256) void attn_mfma(const float* __restrict__ qkv,
                                                 bf16* __restrict__ y) {
    const int qt = blockIdx.x, h = blockIdx.y, b = blockIdx.z;
    const int kvh = h >> 2;
    const int tid = threadIdx.x, wave = tid >> 6, lane = tid & 63;
    const int l15 = lane & 15, g = lane >> 4;
    __shared__ bf16 Ks[32 * KS_LD];       // [key][d] padded
    __shared__ bf16 Vt[128 * VT_LD];      // [d][key] padded
    __shared__ bf16 Pl[4][16 * VT_LD];    // per-wave P tile [qrow][key] padded

    const int qrow0 = qt * 64 + wave * 16;
    short8 qf[4];
    {
        const float* qp = qkv + (size_t)(b * SEQ + qrow0 + l15) * QKV_N + h * HD + g * 8;
#pragma unroll
        for (int c = 0; c < 4; ++c) {
            float tmp[8];
            *(float4*)&tmp[0] = *(const float4*)(qp + c * 32);
            *(float4*)&tmp[4] = *(const float4*)(qp + c * 32 + 4);
            qf[c] = cvt8(tmp);
        }
    }
    f32x4 acc[8] = {};
    float m_[4], l_[4];
#pragma unroll
    for (int r = 0; r < 4; ++r) { m_[r] = -3.0e38f; l_[r] = 0.f; }

    const int kv_end = qt * 64 + 64;
    for (int kv0 = 0; kv0 < kv_end; kv0 += 32) {
        __syncthreads();
        // stage K [32][128] and V^T [128][32] tiles (fp32 -> bf16)
#pragma unroll
        for (int i = 0; i < 2; ++i) {
            int cidx = tid + 256 * i;     // 0..511
            int key = cidx >> 4;          // 0..31
            int d8 = (cidx & 15) * 8;     // 0..120
            const float* kp = qkv + (size_t)(b * SEQ + kv0 + key) * QKV_N + D_MODEL + kvh * HD + d8;
            float tmp[8];
            *(float4*)&tmp[0] = *(const float4*)(kp);
            *(float4*)&tmp[4] = *(const float4*)(kp + 4);
            *(short8*)&Ks[key * KS_LD + d8] = cvt8(tmp);
            *(float4*)&tmp[0] = *(const float4*)(kp + 512);
            *(float4*)&tmp[4] = *(const float4*)(kp + 516);
#pragma unroll
            for (int j = 0; j < 8; ++j)
                Vt[(d8 + j) * VT_LD + key] = __float2bfloat16(tmp[j]);
        }
        __syncthreads();

        // QK^T: two 16-key score tiles
        f32x4 sc[2];
#pragma unroll
        for (int ct = 0; ct < 2; ++ct) {
            sc[ct] = (f32x4){0.f, 0.f, 0.f, 0.f};
            int key = ct * 16 + l15;
#pragma unroll
            for (int c = 0; c < 4; ++c) {
                short8 kf = *(const short8*)&Ks[key * KS_LD + c * 32 + g * 8];
                sc[ct] = __builtin_amdgcn_mfma_f32_16x16x32_bf16(qf[c], kf, sc[ct], 0, 0, 0);
            }
        }
        // scale (fp32, like R9) + causal mask
        int qbase = qrow0 + g * 4;
#pragma unroll
        for (int ct = 0; ct < 2; ++ct) {
            int key = kv0 + ct * 16 + l15;
#pragma unroll
            for (int r = 0; r < 4; ++r) {
                sc[ct][r] *= QSCALE;
                if (key > qbase + r) sc[ct][r] = -3.0e38f;
            }
        }
        // online softmax (rows g*4+r, key-halves over 16 lanes)
#pragma unroll
        for (int r = 0; r < 4; ++r) {
            float mx = fmaxf(sc[0][r], sc[1][r]);
#pragma unroll
            for (int o = 1; o < 16; o <<= 1) mx = fmaxf(mx, __shfl_xor(mx, o));
            float mn = fmaxf(m_[r], mx);
            float alpha = __expf(m_[r] - mn);
            m_[r] = mn;
            l_[r] *= alpha;
#pragma unroll
            for (int nt = 0; nt < 8; ++nt) acc[nt][r] *= alpha;
            float p0 = __expf(sc[0][r] - mn);
            float p1 = __expf(sc[1][r] - mn);
            int row = g * 4 + r;
            Pl[wave][row * VT_LD + l15] = __float2bfloat16(p0);
            Pl[wave][row * VT_LD + 16 + l15] = __float2bfloat16(p1);
            float s2 = p0 + p1;
#pragma unroll
            for (int o = 1; o < 16; o <<= 1) s2 += __shfl_xor(s2, o);
            l_[r] += s2;
        }
        // PV
        short8 pf = *(const short8*)&Pl[wave][l15 * VT_LD + g * 8];
#pragma unroll
        for (int nt = 0; nt < 8; ++nt) {
            int d = nt * 16 + l15;
            short8 vf = *(const short8*)&Vt[d * VT_LD + g * 8];
            acc[nt] = __builtin_amdgcn_mfma_f32_16x16x32_bf16(pf, vf, acc[nt], 0, 0, 0);
        }
    }
    int qrow = qrow0 + g * 4;
#pragma unroll
    for (int nt = 0; nt < 8; ++nt) {
        int d = nt * 16 + l15;
#pragma unroll
        for (int r = 0; r < 4; ++r)
            y[(size_t)(b * SEQ + qrow + r) * D_MODEL + h * HD + d] =
                __float2bfloat16(acc[nt][r] / l_[r]);
    }
}

extern "C" void kernel_launch(void* const* d_in, const int* in_sizes, int n_in,
                              void* d_out, int out_size, void* d_ws, size_t ws_size,
                              hipStream_t stream) {
    const float* x  = (const float*)d_in[0];
    const float* wq = (const float*)d_in[1];
    const float* wk = (const float*)d_in[2];
    const float* wv = (const float*)d_in[3];
    const float* wo = (const float*)d_in[4];

    // Layout:
    //   ws (≥50.33MB proven): qkv fp32 [4096][3072] (phases 2-3);
    //                          outf fp32 [4096][2048] @0 (phase 4, qkv dead)
    //   d_out (33.55MB): phase 1-2: xb bf16 @0, wqkvT bf16 @+8.39M el
    //                    phase 3-4: ybb bf16 @0, woT bf16 @+8.39M el (xb/wqkvT dead)
    //   final: memcpy outf -> d_out
    float* qkv   = (float*)d_ws;
    float* outf  = (float*)d_ws;
    bf16*  xb    = (bf16*)d_out;
    bf16*  wqkvT = (bf16*)d_out + (size_t)NTOK * D_MODEL;
    bf16*  ybb   = (bf16*)d_out;
    bf16*  woT   = (bf16*)d_out + (size_t)NTOK * D_MODEL;

    // phase 1: converts into d_out scratch
    conv_naive<<<dim3((NTOK * D_MODEL + 255) / 256), 256, 0, stream>>>(x, xb, (size_t)NTOK * D_MODEL);
    ct_naive<<<dim3((2048 * 2048 + 255) / 256), 256, 0, stream>>>(wq, wqkvT, 2048, 2048);
    ct_naive<<<dim3((2048 * 512 + 255) / 256), 256, 0, stream>>>(wk, wqkvT + (size_t)2048 * 2048, 2048, 512);
    ct_naive<<<dim3((2048 * 512 + 255) / 256), 256, 0, stream>>>(wv, wqkvT + (size_t)2560 * 2048, 2048, 512);

    // phase 2: QKV projection via MFMA (fp32 out to ws) + RoPE fp32
    gemm_bt<float><<<dim3(QKV_N / 128, NTOK / 128), 256, 0, stream>>>(xb, wqkvT, qkv, NTOK, QKV_N, D_MODEL);
    rope_f32<<<dim3(NTOK * 1280 / 256), 256, 0, stream>>>(qkv);

    // phase 3: MFMA attention (fp32 in, bf16 out) -> ybb; wo^T -> woT (both d_out scratch)
    attn_mfma<<<dim3(SEQ / 64, NHEADS, BATCH), 256, 0, stream>>>(qkv, ybb);
    ct_naive<<<dim3((2048 * 2048 + 255) / 256), 256, 0, stream>>>(wo, woT, 2048, 2048);

    // phase 4: out-projection -> outf (ws, qkv dead), then D2D to d_out
    gemm_bt<float><<<dim3(D_MODEL / 128, NTOK / 128), 256, 0, stream>>>(ybb, woT, outf, NTOK, D_MODEL, D_MODEL);
    hipMemcpyAsync(d_out, outf, (size_t)NTOK * D_MODEL * sizeof(float),
                   hipMemcpyDeviceToDevice, stream);
}

// Round 12
// 391.014 us; speedup vs baseline: 50.5171x; 1.7609x over previous
//
#include <hip/hip_runtime.h>
#include <hip/hip_bf16.h>
#include <stdint.h>

typedef __hip_bfloat16 bf16;
typedef __attribute__((ext_vector_type(8))) short short8;
typedef __attribute__((ext_vector_type(4))) float f32x4;

#define D_MODEL 2048
#define NHEADS 16
#define NKV 4
#define HD 128
#define BATCH 2
#define SEQ 2048
#define NTOK (BATCH*SEQ)
#define QKV_N 3072
#define QSCALE 0.08838834764831845f

// ---------------- naive convert: fp32 -> bf16, 1 thread/element ----------------
__global__ __launch_bounds__(256) void conv_naive(const float* __restrict__ in,
                                                  bf16* __restrict__ out, size_t n) {
    size_t i = (size_t)blockIdx.x * 256 + threadIdx.x;
    if (i < n) out[i] = __float2bfloat16(in[i]);
}

// ------- naive convert-transpose: in fp32 [K][N] -> out bf16 [N][K] -------
__global__ __launch_bounds__(256) void ct_naive(const float* __restrict__ in,
                                                bf16* __restrict__ out, int K, int N) {
    size_t i = (size_t)blockIdx.x * 256 + threadIdx.x;
    if (i >= (size_t)K * N) return;
    int k = (int)(i / N), n = (int)(i % N);
    out[(size_t)n * K + k] = __float2bfloat16(in[i]);
}

// ------------- GEMM: C[M][N] = A[M][K] * Bt[N][K]^T (m97 structure), OutT store -------------
template <typename OutT>
__global__ __launch_bounds__(256) void gemm_bt(const bf16* __restrict__ A,
                                               const bf16* __restrict__ Bt,
                                               OutT* __restrict__ C, int M, int N, int K) {
    __shared__ bf16 As[128 * 32];
    __shared__ bf16 Bs[128 * 32];
    const int m0 = blockIdx.y * 128, n0 = blockIdx.x * 128;
    const int tid = threadIdx.x;
    const int wave = tid >> 6, lane = tid & 63;
    const int wr = wave >> 1, wc = wave & 1;
    const int l15 = lane & 15, g = lane >> 4;
    const int srow = lane >> 2;
    const int sk8 = (lane & 3) * 8;
    f32x4 acc[4][4] = {};

    for (int k0 = 0; k0 < K; k0 += 32) {
        __syncthreads();
#pragma unroll
        for (int i = 0; i < 2; ++i) {
            int chunk = wave * 2 + i;
            const bf16* ga = A + (size_t)(m0 + chunk * 16 + srow) * K + k0 + sk8;
            bf16* la = As + chunk * 512 + lane * 8;
            __builtin_amdgcn_global_load_lds((const __attribute__((address_space(1))) void*)ga,
                                             (__attribute__((address_space(3))) void*)la, 16, 0, 0);
            const bf16* gb = Bt + (size_t)(n0 + chunk * 16 + srow) * K + k0 + sk8;
            bf16* lb = Bs + chunk * 512 + lane * 8;
            __builtin_amdgcn_global_load_lds((const __attribute__((address_space(1))) void*)gb,
                                             (__attribute__((address_space(3))) void*)lb, 16, 0, 0);
        }
        __syncthreads();
        short8 af[4], bfr[4];
#pragma unroll
        for (int mi = 0; mi < 4; ++mi)
            af[mi] = *(const short8*)&As[(wr * 64 + mi * 16 + l15) * 32 + g * 8];
#pragma unroll
        for (int ni = 0; ni < 4; ++ni)
            bfr[ni] = *(const short8*)&Bs[(wc * 64 + ni * 16 + l15) * 32 + g * 8];
#pragma unroll
        for (int mi = 0; mi < 4; ++mi)
#pragma unroll
            for (int ni = 0; ni < 4; ++ni)
                acc[mi][ni] = __builtin_amdgcn_mfma_f32_16x16x32_bf16(af[mi], bfr[ni], acc[mi][ni], 0, 0, 0);
    }
#pragma unroll
    for (int mi = 0; mi < 4; ++mi)
#pragma unroll
        for (int ni = 0; ni < 4; ++ni) {
            int row = m0 + wr * 64 + mi * 16 + g * 4;
            int col = n0 + wc * 64 + ni * 16 + l15;
#pragma unroll
            for (int r = 0; r < 4; ++r) {
                float v = acc[mi][ni][r];
                if constexpr (__is_same(OutT, float))
                    C[(size_t)(row + r) * N + col] = v;
                else
                    C[(size_t)(row + r) * N + col] = __float2bfloat16(v);
            }
        }
}

// ---- fused RoPE + fp32->bf16 convert: qkv fp32 -> qkvb bf16 (all 3072 cols) ----
// pairs: pc2 = col/2; head = pc2>>6 (0-15 q, 16-19 k, 20-23 v); rope on head<20.
__global__ __launch_bounds__(256) void rope_conv(const float* __restrict__ qkv,
                                                 bf16* __restrict__ qkvb) {
    int idx = blockIdx.x * 256 + threadIdx.x;      // < NTOK*1536
    int token = idx / 1536;
    int pc2 = idx - token * 1536;
    size_t base = (size_t)token * QKV_N + 2 * pc2;
    float2 e = *(const float2*)(qkv + base);
    int head = pc2 >> 6;
    float o0 = e.x, o1 = e.y;
    if (head < 20) {
        int i = pc2 & 63;
        int s = token & (SEQ - 1);
        double inv_freq = pow(10000.0, -(double)i / 64.0);
        double sn_d, cs_d;
        sincos((double)s * inv_freq, &sn_d, &cs_d);
        float cs = (float)cs_d, sn = (float)sn_d;
        o0 = e.x * cs - e.y * sn;
        o1 = e.y * cs + e.x * sn;
    }
    union { unsigned int u; bf16 e2[2]; } w;
    w.e2[0] = __float2bfloat16(o0);
    w.e2[1] = __float2bfloat16(o1);
    *(unsigned int*)(qkvb + base) = w.u;
}

// ------- MFMA flash attention v2: bf16 qkv, swizzled LDS, balanced qt pairs -------
// grid (16, NHEADS, BATCH), 256 thr. Block bx handles qt = bx and 31-bx (66 tiles).
#define SWZ(key, d)  ((d) ^ (((key) & 7) << 3))
#define PL_LD 72
__global__ __launch_bounds__(256) void attn2(const bf16* __restrict__ qkv,
                                             bf16* __restrict__ y) {
    const int bx = blockIdx.x, h = blockIdx.y, b = blockIdx.z;
    const int kvh = h >> 2;
    const int tid = threadIdx.x, wave = tid >> 6, lane = tid & 63;
    const int l15 = lane & 15, g = lane >> 4;
    __shared__ bf16 Ks[32 * 128];        // [key][d], XOR-swizzled
    __shared__ bf16 Vr[32 * 128];        // V rows,   XOR-swizzled
    __shared__ bf16 Vt[128 * 32];        // [d][key], XOR-swizzled ((d&3)<<3)
    __shared__ bf16 Pl[4][16 * PL_LD];   // per-wave P [qrow][key], 144B rows
    const int td = tid & 127, tkh = tid >> 7;   // transpose: d, key-half

    for (int half = 0; half < 2; ++half) {
        const int qt = half ? (31 - bx) : bx;
        const int qrow0 = qt * 64 + wave * 16;
        short8 qf[4];
        {
            const bf16* qp = qkv + (size_t)(b * SEQ + qrow0 + l15) * QKV_N + h * HD + g * 8;
#pragma unroll
            for (int c = 0; c < 4; ++c) qf[c] = *(const short8*)(qp + c * 32);
        }
        f32x4 acc[8] = {};
        float m_[4], l_[4];
#pragma unroll
        for (int r = 0; r < 4; ++r) { m_[r] = -3.0e38f; l_[r] = 0.f; }

        const int kv_end = qt * 64 + 64;
        for (int kv0 = 0; kv0 < kv_end; kv0 += 32) {
            // stage K rows + V rows (bf16 int4 copies, swizzled dest)
#pragma unroll
            for (int i = 0; i < 2; ++i) {
                int cidx = tid + 256 * i;     // 0..511
                int key = cidx >> 4;          // 0..31
                int d8 = (cidx & 15) * 8;     // 0..120
                const bf16* kp = qkv + (size_t)(b * SEQ + kv0 + key) * QKV_N + D_MODEL + kvh * HD + d8;
                *(int4*)&Ks[key * 128 + SWZ(key, d8)] = *(const int4*)kp;
                *(int4*)&Vr[key * 128 + SWZ(key, d8)] = *(const int4*)(kp + 512);
            }
            __syncthreads();

            // transpose V: thread owns (d=td, keys tkh*16..+15)
            {
                union { short8 v; bf16 e[8]; } u0, u1;
#pragma unroll
                for (int j = 0; j < 8; ++j)
                    u0.e[j] = Vr[(tkh * 16 + j) * 128 + SWZ(j, td)];
#pragma unroll
                for (int j = 0; j < 8; ++j)
                    u1.e[j] = Vr[(tkh * 16 + 8 + j) * 128 + SWZ(j, td)];
                int swz = (td & 3) << 3;
                *(short8*)&Vt[td * 32 + ((tkh * 16) ^ swz)] = u0.v;
                *(short8*)&Vt[td * 32 + ((tkh * 16 + 8) ^ swz)] = u1.v;
            }

            // QK^T (reads Ks, ready since stage is pre-barrier)
            f32x4 sc[2];
#pragma unroll
            for (int ct = 0; ct < 2; ++ct) {
                sc[ct] = (f32x4){0.f, 0.f, 0.f, 0.f};
                int key = ct * 16 + l15;
#pragma unroll
                for (int c = 0; c < 4; ++c) {
                    short8 kf = *(const short8*)&Ks[key * 128 + SWZ(key, c * 32 + g * 8)];
                    sc[ct] = __builtin_amdgcn_mfma_f32_16x16x32_bf16(qf[c], kf, sc[ct], 0, 0, 0);
                }
            }
            // scale + causal mask
            int qbase = qrow0 + g * 4;
#pragma unroll
            for (int ct = 0; ct < 2; ++ct) {
                int key = kv0 + ct * 16 + l15;
#pragma unroll
                for (int r = 0; r < 4; ++r) {
                    sc[ct][r] *= QSCALE;
                    if (key > qbase + r) sc[ct][r] = -3.0e38f;
                }
            }
            // online softmax
#pragma unroll
            for (int r = 0; r < 4; ++r) {
                float mx = fmaxf(sc[0][r], sc[1][r]);
#pragma unroll
                for (int o = 1; o < 16; o <<= 1) mx = fmaxf(mx, __shfl_xor(mx, o));
                float mn = fmaxf(m_[r], mx);
                float alpha = __expf(m_[r] - mn);
                m_[r] = mn;
                l_[r] *= alpha;
#pragma unroll
                for (int nt = 0; nt < 8; ++nt) acc[nt][r] *= alpha;
                float p0 = __expf(sc[0][r] - mn);
                float p1 = __expf(sc[1][r] - mn);
                int row = g * 4 + r;
                Pl[wave][row * PL_LD + l15] = __float2bfloat16(p0);
                Pl[wave][row * PL_LD + 16 + l15] = __float2bfloat16(p1);
                float s2 = p0 + p1;
#pragma unroll
                for (int o = 1; o < 16; o <<= 1) s2 += __shfl_xor(s2, o);
                l_[r] += s2;
            }
            __syncthreads();   // Vt complete; Ks/Vr free to restage next iter

            // PV
            short8 pf = *(const short8*)&Pl[wave][l15 * PL_LD + g * 8];
#pragma unroll
            for (int nt = 0; nt < 8; ++nt) {
                int d = nt * 16 + l15;
                short8 vf = *(const short8*)&Vt[d * 32 + ((g * 8) ^ ((d & 3) << 3))];
                acc[nt] = __builtin_amdgcn_mfma_f32_16x16x32_bf16(pf, vf, acc[nt], 0, 0, 0);
            }
        }
        // epilogue for this qt
        int qrow = qrow0 + g * 4;
#pragma unroll
        for (int nt = 0; nt < 8; ++nt) {
            int d = nt * 16 + l15;
#pragma unroll
            for (int r = 0; r < 4; ++r)
                y[(size_t)(b * SEQ + qrow + r) * D_MODEL + h * HD + d] =
                    __float2bfloat16(acc[nt][r] / l_[r]);
        }
        __syncthreads();   // LDS reuse across halves
    }
}

extern "C" void kernel_launch(void* const* d_in, const int* in_sizes, int n_in,
                              void* d_out, int out_size, void* d_ws, size_t ws_size,
                              hipStream_t stream) {
    const float* x  = (const float*)d_in[0];
    const float* wq = (const float*)d_in[1];
    const float* wk = (const float*)d_in[2];
    const float* wv = (const float*)d_in[3];
    const float* wo = (const float*)d_in[4];

    // Layout:
    //   ws (50.33MB proven): qkv fp32 [4096][3072] (ph2, dead after rope_conv)
    //       then: ybb bf16 @0 (16.78MB), woT bf16 @+8.39M el (8.39MB)
    //   d_out (33.55MB): ph1: xb bf16 @0, wqkvT bf16 @+8.39M el (dead after gemm1)
    //       ph2.5-3: qkvb bf16 [4096][3072] @0 (25.17MB, dead after attn)
    //       ph4: final fp32 output (gemm2 writes directly)
    float* qkv   = (float*)d_ws;
    bf16*  ybb   = (bf16*)d_ws;
    bf16*  woT   = (bf16*)d_ws + (size_t)NTOK * D_MODEL;
    bf16*  xb    = (bf16*)d_out;
    bf16*  wqkvT = (bf16*)d_out + (size_t)NTOK * D_MODEL;
    bf16*  qkvb  = (bf16*)d_out;
    float* outf  = (float*)d_out;

    // phase 1: converts into d_out scratch
    conv_naive<<<dim3((NTOK * D_MODEL + 255) / 256), 256, 0, stream>>>(x, xb, (size_t)NTOK * D_MODEL);
    ct_naive<<<dim3((2048 * 2048 + 255) / 256), 256, 0, stream>>>(wq, wqkvT, 2048, 2048);
    ct_naive<<<dim3((2048 * 512 + 255) / 256), 256, 0, stream>>>(wk, wqkvT + (size_t)2048 * 2048, 2048, 512);
    ct_naive<<<dim3((2048 * 512 + 255) / 256), 256, 0, stream>>>(wv, wqkvT + (size_t)2560 * 2048, 2048, 512);

    // phase 2: QKV projection (fp32 out to ws)
    gemm_bt<float><<<dim3(QKV_N / 128, NTOK / 128), 256, 0, stream>>>(xb, wqkvT, qkv, NTOK, QKV_N, D_MODEL);
    // phase 2.5: fused RoPE + convert -> qkvb (d_out; xb/wqkvT dead)
    rope_conv<<<dim3(NTOK * 1536 / 256), 256, 0, stream>>>(qkv, qkvb);
    // wo^T into ws (qkv fp32 dead)
    ct_naive<<<dim3((2048 * 2048 + 255) / 256), 256, 0, stream>>>(wo, woT, 2048, 2048);

    // phase 3: attention (bf16 in, bf16 out) -> ybb (ws)
    attn2<<<dim3(16, NHEADS, BATCH), 256, 0, stream>>>(qkvb, ybb);

    // phase 4: out-projection -> fp32 directly into d_out (qkvb dead)
    gemm_bt<float><<<dim3(D_MODEL / 128, NTOK / 128), 256, 0, stream>>>(ybb, woT, outf, NTOK, D_MODEL, D_MODEL);
}

// Round 13
// 288.038 us; speedup vs baseline: 68.5772x; 1.3575x over previous
//
#include <hip/hip_runtime.h>
#include <hip/hip_bf16.h>
#include <stdint.h>

typedef __hip_bfloat16 bf16;
typedef __attribute__((ext_vector_type(8))) short short8;
typedef __attribute__((ext_vector_type(4))) float f32x4;

#define D_MODEL 2048
#define NHEADS 16
#define NKV 4
#define HD 128
#define BATCH 2
#define SEQ 2048
#define NTOK (BATCH*SEQ)
#define QKV_N 3072
#define QSCALE 0.08838834764831845f

// ---------------- trig table: [s][i] -> (cos, sin), double precision ----------------
__global__ __launch_bounds__(256) void trig_kernel(float2* __restrict__ tab) {
    int idx = blockIdx.x * 256 + threadIdx.x;       // < 2048*64
    int s = idx >> 6, i = idx & 63;
    double inv_freq = pow(10000.0, -(double)i / 64.0);
    double sn, cs;
    sincos((double)s * inv_freq, &sn, &cs);
    tab[idx] = make_float2((float)cs, (float)sn);
}

// ---------------- vectorized convert: fp32 -> bf16 (8 el/thread) ----------------
__global__ __launch_bounds__(256) void conv8(const float* __restrict__ in,
                                             bf16* __restrict__ out, int n8) {
    int idx = blockIdx.x * 256 + threadIdx.x;
    if (idx >= n8) return;
    const float4* p = (const float4*)(in + (size_t)idx * 8);
    float4 a = p[0], b = p[1];
    union { short8 v; bf16 e[8]; } u;
    u.e[0] = __float2bfloat16(a.x); u.e[1] = __float2bfloat16(a.y);
    u.e[2] = __float2bfloat16(a.z); u.e[3] = __float2bfloat16(a.w);
    u.e[4] = __float2bfloat16(b.x); u.e[5] = __float2bfloat16(b.y);
    u.e[6] = __float2bfloat16(b.z); u.e[7] = __float2bfloat16(b.w);
    *(short8*)(out + (size_t)idx * 8) = u.v;
}

// ------- convert-transpose: fp32 [K][N] -> bf16 [N][K]; TILE_LD=68 (272B rows, aligned) -------
#define TILE_LD 68
__global__ __launch_bounds__(256) void ct64(const float* __restrict__ in,
                                            bf16* __restrict__ out, int K, int N) {
    __shared__ float tile[64 * TILE_LD];
    int n0 = blockIdx.x * 64, k0 = blockIdx.y * 64;
    int t = threadIdx.x;
#pragma unroll
    for (int i = 0; i < 4; ++i) {
        int idx = t + 256 * i;
        int r = idx >> 4;
        int c4 = (idx & 15) * 4;
        *(float4*)&tile[r * TILE_LD + c4] = *(const float4*)(in + (size_t)(k0 + r) * N + n0 + c4);
    }
    __syncthreads();
#pragma unroll
    for (int i = 0; i < 2; ++i) {
        int idx = t + 256 * i;
        int n = idx >> 3;
        int kc = (idx & 7) * 8;
        union { short8 v; bf16 e[8]; } u;
#pragma unroll
        for (int j = 0; j < 8; ++j) u.e[j] = __float2bfloat16(tile[(kc + j) * TILE_LD + n]);
        *(short8*)(out + (size_t)(n0 + n) * K + k0 + kc) = u.v;
    }
}

// ------------- GEMM (m97 structure); optional fused-RoPE bf16 epilogue -------------
template <typename OutT, bool ROPE>
__global__ __launch_bounds__(256) void gemm_bt(const bf16* __restrict__ A,
                                               const bf16* __restrict__ Bt,
                                               OutT* __restrict__ C, int M, int N, int K,
                                               const float2* __restrict__ trig) {
    __shared__ bf16 As[128 * 32];
    __shared__ bf16 Bs[128 * 32];
    const int m0 = blockIdx.y * 128, n0 = blockIdx.x * 128;
    const int tid = threadIdx.x;
    const int wave = tid >> 6, lane = tid & 63;
    const int wr = wave >> 1, wc = wave & 1;
    const int l15 = lane & 15, g = lane >> 4;
    const int srow = lane >> 2;
    const int sk8 = (lane & 3) * 8;
    f32x4 acc[4][4] = {};

    for (int k0 = 0; k0 < K; k0 += 32) {
        __syncthreads();
#pragma unroll
        for (int i = 0; i < 2; ++i) {
            int chunk = wave * 2 + i;
            const bf16* ga = A + (size_t)(m0 + chunk * 16 + srow) * K + k0 + sk8;
            bf16* la = As + chunk * 512 + lane * 8;
            __builtin_amdgcn_global_load_lds((const __attribute__((address_space(1))) void*)ga,
                                             (__attribute__((address_space(3))) void*)la, 16, 0, 0);
            const bf16* gb = Bt + (size_t)(n0 + chunk * 16 + srow) * K + k0 + sk8;
            bf16* lb = Bs + chunk * 512 + lane * 8;
            __builtin_amdgcn_global_load_lds((const __attribute__((address_space(1))) void*)gb,
                                             (__attribute__((address_space(3))) void*)lb, 16, 0, 0);
        }
        __syncthreads();
        short8 af[4], bfr[4];
#pragma unroll
        for (int mi = 0; mi < 4; ++mi)
            af[mi] = *(const short8*)&As[(wr * 64 + mi * 16 + l15) * 32 + g * 8];
#pragma unroll
        for (int ni = 0; ni < 4; ++ni)
            bfr[ni] = *(const short8*)&Bs[(wc * 64 + ni * 16 + l15) * 32 + g * 8];
#pragma unroll
        for (int mi = 0; mi < 4; ++mi)
#pragma unroll
            for (int ni = 0; ni < 4; ++ni)
                acc[mi][ni] = __builtin_amdgcn_mfma_f32_16x16x32_bf16(af[mi], bfr[ni], acc[mi][ni], 0, 0, 0);
    }
#pragma unroll
    for (int mi = 0; mi < 4; ++mi)
#pragma unroll
        for (int ni = 0; ni < 4; ++ni) {
            int row = m0 + wr * 64 + mi * 16 + g * 4;
            int col = n0 + wc * 64 + ni * 16 + l15;
#pragma unroll
            for (int r = 0; r < 4; ++r) {
                float v = acc[mi][ni][r];
                if constexpr (ROPE) {
                    float partner = __shfl_xor(v, 1);   // pair lane (col^1)
                    if (col < 2560) {                    // q + k cols get rope
                        int s = (row + r) & (SEQ - 1);
                        int i2 = (col & 127) >> 1;
                        float2 t = trig[s * 64 + i2];
                        v = (col & 1) ? (v * t.x + partner * t.y)
                                      : (v * t.x - partner * t.y);
                    }
                }
                if constexpr (__is_same(OutT, float))
                    C[(size_t)(row + r) * N + col] = v;
                else
                    C[(size_t)(row + r) * N + col] = __float2bfloat16(v);
            }
        }
}

// ------- MFMA flash attention v3: KVBLK=64, conflict-free Vt/Pl (stride 72), skip-rescale -------
// grid (16, NHEADS, BATCH), 256 thr. Block bx handles qt = bx and 31-bx (33 kv-tiles of 64).
#define SWZ(key, d)  ((d) ^ (((key) & 7) << 3))
#define VT_LD 72
#define PL_LD 72
__global__ __launch_bounds__(256) void attn3(const bf16* __restrict__ qkv,
                                             bf16* __restrict__ y) {
    const int bx = blockIdx.x, h = blockIdx.y, b = blockIdx.z;
    const int kvh = h >> 2;
    const int tid = threadIdx.x, wave = tid >> 6, lane = tid & 63;
    const int l15 = lane & 15, g = lane >> 4;
    __shared__ bf16 Ks[64 * 128];        // [key][d], XOR-swizzled rows
    __shared__ bf16 Vr[64 * 128];        // V rows, XOR-swizzled
    __shared__ bf16 Vt[128 * VT_LD];     // [d][key], 144B rows (conflict-free b128)
    __shared__ bf16 Pl[4][16 * PL_LD];   // per-wave P [qrow][key], 144B rows
    const int td = tid & 127, tkh = tid >> 7;

    for (int half = 0; half < 2; ++half) {
        const int qt = half ? (31 - bx) : bx;
        const int qrow0 = qt * 64 + wave * 16;
        short8 qf[4];
        {
            const bf16* qp = qkv + (size_t)(b * SEQ + qrow0 + l15) * QKV_N + h * HD + g * 8;
#pragma unroll
            for (int c = 0; c < 4; ++c) qf[c] = *(const short8*)(qp + c * 32);
        }
        f32x4 acc[8] = {};
        float m_[4], l_[4];
#pragma unroll
        for (int r = 0; r < 4; ++r) { m_[r] = -3.0e38f; l_[r] = 0.f; }

        const int kv_end = qt * 64 + 64;
        for (int kv0 = 0; kv0 < kv_end; kv0 += 64) {
            // stage 64 K rows + 64 V rows (int4, swizzled dest)
#pragma unroll
            for (int i = 0; i < 4; ++i) {
                int cidx = tid + 256 * i;     // 0..1023
                int key = cidx >> 4;          // 0..63
                int d8 = (cidx & 15) * 8;     // 0..120
                const bf16* kp = qkv + (size_t)(b * SEQ + kv0 + key) * QKV_N + D_MODEL + kvh * HD + d8;
                *(int4*)&Ks[key * 128 + SWZ(key, d8)] = *(const int4*)kp;
                *(int4*)&Vr[key * 128 + SWZ(key, d8)] = *(const int4*)(kp + 512);
            }
            __syncthreads();

            // transpose V: thread owns (d=td, keys tkh*32..+31)
            {
                union { short8 v; bf16 e[8]; } u[4];
#pragma unroll
                for (int q4 = 0; q4 < 4; ++q4)
#pragma unroll
                    for (int j = 0; j < 8; ++j)
                        u[q4].e[j] = Vr[(tkh * 32 + q4 * 8 + j) * 128 + SWZ(q4 * 8 + j, td)];
#pragma unroll
                for (int q4 = 0; q4 < 4; ++q4)
                    *(short8*)&Vt[td * VT_LD + tkh * 32 + q4 * 8] = u[q4].v;
            }

            // QK^T: 4 x 16-key score tiles
            f32x4 sc[4];
#pragma unroll
            for (int ct = 0; ct < 4; ++ct) {
                sc[ct] = (f32x4){0.f, 0.f, 0.f, 0.f};
                int key = ct * 16 + l15;
#pragma unroll
                for (int c = 0; c < 4; ++c) {
                    short8 kf = *(const short8*)&Ks[key * 128 + SWZ(key, c * 32 + g * 8)];
                    sc[ct] = __builtin_amdgcn_mfma_f32_16x16x32_bf16(qf[c], kf, sc[ct], 0, 0, 0);
                }
            }
            // scale + causal mask
            int qbase = qrow0 + g * 4;
#pragma unroll
            for (int ct = 0; ct < 4; ++ct) {
                int key = kv0 + ct * 16 + l15;
#pragma unroll
                for (int r = 0; r < 4; ++r) {
                    sc[ct][r] *= QSCALE;
                    if (key > qbase + r) sc[ct][r] = -3.0e38f;
                }
            }
            // online softmax with skip-rescale
#pragma unroll
            for (int r = 0; r < 4; ++r) {
                float mx = fmaxf(fmaxf(sc[0][r], sc[1][r]), fmaxf(sc[2][r], sc[3][r]));
#pragma unroll
                for (int o = 1; o < 16; o <<= 1) mx = fmaxf(mx, __shfl_xor(mx, o));
                if (mx > m_[r]) {
                    float alpha = __expf(m_[r] - mx);
                    m_[r] = mx;
                    l_[r] *= alpha;
#pragma unroll
                    for (int nt = 0; nt < 8; ++nt) acc[nt][r] *= alpha;
                }
                float p0 = __expf(sc[0][r] - m_[r]);
                float p1 = __expf(sc[1][r] - m_[r]);
                float p2 = __expf(sc[2][r] - m_[r]);
                float p3 = __expf(sc[3][r] - m_[r]);
                int row = g * 4 + r;
                Pl[wave][row * PL_LD + l15]      = __float2bfloat16(p0);
                Pl[wave][row * PL_LD + 16 + l15] = __float2bfloat16(p1);
                Pl[wave][row * PL_LD + 32 + l15] = __float2bfloat16(p2);
                Pl[wave][row * PL_LD + 48 + l15] = __float2bfloat16(p3);
                float s2 = (p0 + p1) + (p2 + p3);
#pragma unroll
                for (int o = 1; o < 16; o <<= 1) s2 += __shfl_xor(s2, o);
                l_[r] += s2;
            }
            __syncthreads();   // Vt+Pl complete; Ks/Vr free next iter

            // PV: 2 k-steps of 32 keys
            short8 pf0 = *(const short8*)&Pl[wave][l15 * PL_LD + g * 8];
            short8 pf1 = *(const short8*)&Pl[wave][l15 * PL_LD + 32 + g * 8];
#pragma unroll
            for (int nt = 0; nt < 8; ++nt) {
                int d = nt * 16 + l15;
                short8 vf0 = *(const short8*)&Vt[d * VT_LD + g * 8];
                short8 vf1 = *(const short8*)&Vt[d * VT_LD + 32 + g * 8];
                acc[nt] = __builtin_amdgcn_mfma_f32_16x16x32_bf16(pf0, vf0, acc[nt], 0, 0, 0);
                acc[nt] = __builtin_amdgcn_mfma_f32_16x16x32_bf16(pf1, vf1, acc[nt], 0, 0, 0);
            }
        }
        // epilogue for this qt
        int qrow = qrow0 + g * 4;
#pragma unroll
        for (int nt = 0; nt < 8; ++nt) {
            int d = nt * 16 + l15;
#pragma unroll
            for (int r = 0; r < 4; ++r)
                y[(size_t)(b * SEQ + qrow + r) * D_MODEL + h * HD + d] =
                    __float2bfloat16(acc[nt][r] / l_[r]);
        }
        __syncthreads();   // LDS reuse across halves
    }
}

extern "C" void kernel_launch(void* const* d_in, const int* in_sizes, int n_in,
                              void* d_out, int out_size, void* d_ws, size_t ws_size,
                              hipStream_t stream) {
    const float* x  = (const float*)d_in[0];
    const float* wq = (const float*)d_in[1];
    const float* wk = (const float*)d_in[2];
    const float* wv = (const float*)d_in[3];
    const float* wo = (const float*)d_in[4];

    // Layout:
    //   ws (50.33MB proven):
    //     qkvb bf16 [4096][3072] @ el 0            (25.17MB; gemm1 out, attn in)
    //     ybb  bf16 [4096][2048] @ el 12.58M       (16.78MB; attn out, gemm2 in)
    //     woT  bf16 [2048][2048] @ el 20.97M       ( 8.39MB; ends exactly 50.33MB)
    //   d_out (33.55MB scratch until gemm2):
    //     xb    bf16 [4096][2048] @ el 0           (16.78MB; gemm1 A)
    //     wqkvT bf16 [3072][2048] @ el 8.39M       (12.58MB; gemm1 B)
    //     trig  float2 [2048][64] @ el 14.68M      ( 1.05MB)
    //     final: gemm2 writes fp32 output over all of d_out.
    bf16*   qkvb  = (bf16*)d_ws;
    bf16*   ybb   = (bf16*)d_ws + (size_t)NTOK * 3072;
    bf16*   woT   = (bf16*)d_ws + (size_t)NTOK * 3072 + (size_t)NTOK * D_MODEL;
    bf16*   xb    = (bf16*)d_out;
    bf16*   wqkvT = (bf16*)d_out + (size_t)NTOK * D_MODEL;
    float2* trig  = (float2*)((bf16*)d_out + (size_t)NTOK * D_MODEL + (size_t)QKV_N * D_MODEL);
    float*  outf  = (float*)d_out;

    // phase 1: converts + trig table
    conv8<<<dim3(NTOK * D_MODEL / (256 * 8)), 256, 0, stream>>>(x, xb, NTOK * D_MODEL / 8);
    ct64<<<dim3(32, 32), 256, 0, stream>>>(wq, wqkvT, 2048, 2048);
    ct64<<<dim3(8, 32), 256, 0, stream>>>(wk, wqkvT + (size_t)2048 * 2048, 2048, 512);
    ct64<<<dim3(8, 32), 256, 0, stream>>>(wv, wqkvT + (size_t)2560 * 2048, 2048, 512);
    ct64<<<dim3(32, 32), 256, 0, stream>>>(wo, woT, 2048, 2048);
    trig_kernel<<<dim3(SEQ * 64 / 256), 256, 0, stream>>>(trig);

    // phase 2: QKV projection with fused RoPE -> qkvb (bf16, ws)
    gemm_bt<bf16, true><<<dim3(QKV_N / 128, NTOK / 128), 256, 0, stream>>>(
        xb, wqkvT, qkvb, NTOK, QKV_N, D_MODEL, trig);

    // phase 3: attention -> ybb (ws)
    attn3<<<dim3(16, NHEADS, BATCH), 256, 0, stream>>>(qkvb, ybb);

    // phase 4: out-projection -> fp32 directly into d_out (xb/wqkvT/trig dead)
    gemm_bt<float, false><<<dim3(D_MODEL / 128, NTOK / 128), 256, 0, stream>>>(
        ybb, woT, outf, NTOK, D_MODEL, D_MODEL, nullptr);
}

// Round 14
// 278.794 us; speedup vs baseline: 70.8510x; 1.0332x over previous
//
#include <hip/hip_runtime.h>
#include <hip/hip_bf16.h>
#include <stdint.h>

typedef __hip_bfloat16 bf16;
typedef __attribute__((ext_vector_type(8))) short short8;
typedef __attribute__((ext_vector_type(4))) float f32x4;

#define D_MODEL 2048
#define NHEADS 16
#define NKV 4
#define HD 128
#define BATCH 2
#define SEQ 2048
#define NTOK (BATCH*SEQ)
#define QKV_N 3072
#define QSCALE 0.08838834764831845f

// ---------------- trig table: [s][i] -> (cos, sin), double precision ----------------
__global__ __launch_bounds__(256) void trig_kernel(float2* __restrict__ tab) {
    int idx = blockIdx.x * 256 + threadIdx.x;       // < 2048*64
    int s = idx >> 6, i = idx & 63;
    double inv_freq = pow(10000.0, -(double)i / 64.0);
    double sn, cs;
    sincos((double)s * inv_freq, &sn, &cs);
    tab[idx] = make_float2((float)cs, (float)sn);
}

// ---------------- vectorized convert: fp32 -> bf16 (8 el/thread) ----------------
__global__ __launch_bounds__(256) void conv8(const float* __restrict__ in,
                                             bf16* __restrict__ out, int n8) {
    int idx = blockIdx.x * 256 + threadIdx.x;
    if (idx >= n8) return;
    const float4* p = (const float4*)(in + (size_t)idx * 8);
    float4 a = p[0], b = p[1];
    union { short8 v; bf16 e[8]; } u;
    u.e[0] = __float2bfloat16(a.x); u.e[1] = __float2bfloat16(a.y);
    u.e[2] = __float2bfloat16(a.z); u.e[3] = __float2bfloat16(a.w);
    u.e[4] = __float2bfloat16(b.x); u.e[5] = __float2bfloat16(b.y);
    u.e[6] = __float2bfloat16(b.z); u.e[7] = __float2bfloat16(b.w);
    *(short8*)(out + (size_t)idx * 8) = u.v;
}

// ------- convert-transpose: fp32 [K][N] -> bf16 [N][K]; TILE_LD=68 (272B rows, aligned) -------
#define TILE_LD 68
__global__ __launch_bounds__(256) void ct64(const float* __restrict__ in,
                                            bf16* __restrict__ out, int K, int N) {
    __shared__ float tile[64 * TILE_LD];
    int n0 = blockIdx.x * 64, k0 = blockIdx.y * 64;
    int t = threadIdx.x;
#pragma unroll
    for (int i = 0; i < 4; ++i) {
        int idx = t + 256 * i;
        int r = idx >> 4;
        int c4 = (idx & 15) * 4;
        *(float4*)&tile[r * TILE_LD + c4] = *(const float4*)(in + (size_t)(k0 + r) * N + n0 + c4);
    }
    __syncthreads();
#pragma unroll
    for (int i = 0; i < 2; ++i) {
        int idx = t + 256 * i;
        int n = idx >> 3;
        int kc = (idx & 7) * 8;
        union { short8 v; bf16 e[8]; } u;
#pragma unroll
        for (int j = 0; j < 8; ++j) u.e[j] = __float2bfloat16(tile[(kc + j) * TILE_LD + n]);
        *(short8*)(out + (size_t)(n0 + n) * K + k0 + kc) = u.v;
    }
}

// ---- V^T: qkvb v-cols [token][2560+vd] -> vT [(b*512+vd)][s] (bf16, 64x64 LDS tiles) ----
__global__ __launch_bounds__(256) void vt64(const bf16* __restrict__ qkvb,
                                            bf16* __restrict__ vT) {
    __shared__ bf16 tile[64 * 72];    // 144B rows, 16B-aligned
    int vd0 = blockIdx.x * 64, s0 = blockIdx.y * 64, b = blockIdx.z;
    int t = threadIdx.x;
#pragma unroll
    for (int i = 0; i < 2; ++i) {
        int idx = t + 256 * i;        // 0..511
        int r = idx >> 3;             // token 0..63
        int c8 = (idx & 7) * 8;       // vd chunk
        *(int4*)&tile[r * 72 + c8] =
            *(const int4*)(qkvb + (size_t)(b * SEQ + s0 + r) * QKV_N + 2560 + vd0 + c8);
    }
    __syncthreads();
#pragma unroll
    for (int i = 0; i < 2; ++i) {
        int idx = t + 256 * i;
        int vd = idx >> 3;
        int s8 = (idx & 7) * 8;
        union { short8 v; bf16 e[8]; } u;
#pragma unroll
        for (int j = 0; j < 8; ++j) u.e[j] = tile[(s8 + j) * 72 + vd];
        *(short8*)(vT + (size_t)(b * 512 + vd0 + vd) * 2048 + s0 + s8) = u.v;
    }
}

// ------------- GEMM (m97 structure); optional fused-RoPE bf16 epilogue -------------
template <typename OutT, bool ROPE>
__global__ __launch_bounds__(256) void gemm_bt(const bf16* __restrict__ A,
                                               const bf16* __restrict__ Bt,
                                               OutT* __restrict__ C, int M, int N, int K,
                                               const float2* __restrict__ trig) {
    __shared__ bf16 As[128 * 32];
    __shared__ bf16 Bs[128 * 32];
    const int m0 = blockIdx.y * 128, n0 = blockIdx.x * 128;
    const int tid = threadIdx.x;
    const int wave = tid >> 6, lane = tid & 63;
    const int wr = wave >> 1, wc = wave & 1;
    const int l15 = lane & 15, g = lane >> 4;
    const int srow = lane >> 2;
    const int sk8 = (lane & 3) * 8;
    f32x4 acc[4][4] = {};

    for (int k0 = 0; k0 < K; k0 += 32) {
        __syncthreads();
#pragma unroll
        for (int i = 0; i < 2; ++i) {
            int chunk = wave * 2 + i;
            const bf16* ga = A + (size_t)(m0 + chunk * 16 + srow) * K + k0 + sk8;
            bf16* la = As + chunk * 512 + lane * 8;
            __builtin_amdgcn_global_load_lds((const __attribute__((address_space(1))) void*)ga,
                                             (__attribute__((address_space(3))) void*)la, 16, 0, 0);
            const bf16* gb = Bt + (size_t)(n0 + chunk * 16 + srow) * K + k0 + sk8;
            bf16* lb = Bs + chunk * 512 + lane * 8;
            __builtin_amdgcn_global_load_lds((const __attribute__((address_space(1))) void*)gb,
                                             (__attribute__((address_space(3))) void*)lb, 16, 0, 0);
        }
        __syncthreads();
        short8 af[4], bfr[4];
#pragma unroll
        for (int mi = 0; mi < 4; ++mi)
            af[mi] = *(const short8*)&As[(wr * 64 + mi * 16 + l15) * 32 + g * 8];
#pragma unroll
        for (int ni = 0; ni < 4; ++ni)
            bfr[ni] = *(const short8*)&Bs[(wc * 64 + ni * 16 + l15) * 32 + g * 8];
#pragma unroll
        for (int mi = 0; mi < 4; ++mi)
#pragma unroll
            for (int ni = 0; ni < 4; ++ni)
                acc[mi][ni] = __builtin_amdgcn_mfma_f32_16x16x32_bf16(af[mi], bfr[ni], acc[mi][ni], 0, 0, 0);
    }
#pragma unroll
    for (int mi = 0; mi < 4; ++mi)
#pragma unroll
        for (int ni = 0; ni < 4; ++ni) {
            int row = m0 + wr * 64 + mi * 16 + g * 4;
            int col = n0 + wc * 64 + ni * 16 + l15;
#pragma unroll
            for (int r = 0; r < 4; ++r) {
                float v = acc[mi][ni][r];
                if constexpr (ROPE) {
                    float partner = __shfl_xor(v, 1);   // pair lane (col^1)
                    if (col < 2560) {
                        int s = (row + r) & (SEQ - 1);
                        int i2 = (col & 127) >> 1;
                        float2 t = trig[s * 64 + i2];
                        v = (col & 1) ? (v * t.x + partner * t.y)
                                      : (v * t.x - partner * t.y);
                    }
                }
                if constexpr (__is_same(OutT, float))
                    C[(size_t)(row + r) * N + col] = v;
                else
                    C[(size_t)(row + r) * N + col] = __float2bfloat16(v);
            }
        }
}

// ---- MFMA flash attention v4: global_load_lds staging (pre-swizzled source), no transpose ----
// grid (16, NHEADS, BATCH), 256 thr. Block bx handles qt = bx and 31-bx.
// Ks linear: pos key*128+8j holds K element d = 8*(j^(key&7))  -> read addr d^((key&7)<<3)
// Vt linear: pos d*64+8j  holds key  k = kv0 + 8*(j^(d&7))     -> read addr k^((d&7)<<3)
#define PL_LD 72
__global__ __launch_bounds__(256) void attn4(const bf16* __restrict__ qkv,
                                             const bf16* __restrict__ vT,
                                             bf16* __restrict__ y) {
    const int bx = blockIdx.x, h = blockIdx.y, b = blockIdx.z;
    const int kvh = h >> 2;
    const int tid = threadIdx.x, wave = tid >> 6, lane = tid & 63;
    const int l15 = lane & 15, g = lane >> 4;
    __shared__ bf16 Ks[64 * 128];
    __shared__ bf16 Vt[128 * 64];
    __shared__ bf16 Pl[4][16 * PL_LD];

    for (int half = 0; half < 2; ++half) {
        const int qt = half ? (31 - bx) : bx;
        const int qrow0 = qt * 64 + wave * 16;
        short8 qf[4];
        {
            const bf16* qp = qkv + (size_t)(b * SEQ + qrow0 + l15) * QKV_N + h * HD + g * 8;
#pragma unroll
            for (int c = 0; c < 4; ++c) qf[c] = *(const short8*)(qp + c * 32);
        }
        f32x4 acc[8] = {};
        float m_[4], l_[4];
#pragma unroll
        for (int r = 0; r < 4; ++r) { m_[r] = -3.0e38f; l_[r] = 0.f; }

        const int kv_end = qt * 64 + 64;
        for (int kv0 = 0; kv0 < kv_end; kv0 += 64) {
            // stage K (64x128) + V^T (128x64) via global_load_lds, source pre-swizzled
#pragma unroll
            for (int i = 0; i < 4; ++i) {
                int cidx = tid + 256 * i;           // 0..1023
                int key = cidx >> 4, j = cidx & 15;
                const bf16* gk = qkv + (size_t)(b * SEQ + kv0 + key) * QKV_N + D_MODEL
                               + kvh * HD + 8 * (j ^ (key & 7));
                __builtin_amdgcn_global_load_lds(
                    (const __attribute__((address_space(1))) void*)gk,
                    (__attribute__((address_space(3))) void*)(Ks + cidx * 8), 16, 0, 0);
                int d = cidx >> 3, j2 = cidx & 7;
                const bf16* gv = vT + (size_t)(b * 512 + kvh * HD + d) * 2048
                               + kv0 + 8 * (j2 ^ (d & 7));
                __builtin_amdgcn_global_load_lds(
                    (const __attribute__((address_space(1))) void*)gv,
                    (__attribute__((address_space(3))) void*)(Vt + cidx * 8), 16, 0, 0);
            }
            __syncthreads();

            // QK^T: 4 x 16-key score tiles
            f32x4 sc[4];
#pragma unroll
            for (int ct = 0; ct < 4; ++ct) {
                sc[ct] = (f32x4){0.f, 0.f, 0.f, 0.f};
                int key = ct * 16 + l15;
                int ksw = (key & 7) << 3;
#pragma unroll
                for (int c = 0; c < 4; ++c) {
                    short8 kf = *(const short8*)&Ks[key * 128 + ((c * 32 + g * 8) ^ ksw)];
                    sc[ct] = __builtin_amdgcn_mfma_f32_16x16x32_bf16(qf[c], kf, sc[ct], 0, 0, 0);
                }
            }
            // scale + causal mask
            int qbase = qrow0 + g * 4;
#pragma unroll
            for (int ct = 0; ct < 4; ++ct) {
                int key = kv0 + ct * 16 + l15;
#pragma unroll
                for (int r = 0; r < 4; ++r) {
                    sc[ct][r] *= QSCALE;
                    if (key > qbase + r) sc[ct][r] = -3.0e38f;
                }
            }
            // online softmax with skip-rescale
#pragma unroll
            for (int r = 0; r < 4; ++r) {
                float mx = fmaxf(fmaxf(sc[0][r], sc[1][r]), fmaxf(sc[2][r], sc[3][r]));
#pragma unroll
                for (int o = 1; o < 16; o <<= 1) mx = fmaxf(mx, __shfl_xor(mx, o));
                if (mx > m_[r]) {
                    float alpha = __expf(m_[r] - mx);
                    m_[r] = mx;
                    l_[r] *= alpha;
#pragma unroll
                    for (int nt = 0; nt < 8; ++nt) acc[nt][r] *= alpha;
                }
                float p0 = __expf(sc[0][r] - m_[r]);
                float p1 = __expf(sc[1][r] - m_[r]);
                float p2 = __expf(sc[2][r] - m_[r]);
                float p3 = __expf(sc[3][r] - m_[r]);
                int row = g * 4 + r;
                Pl[wave][row * PL_LD + l15]      = __float2bfloat16(p0);
                Pl[wave][row * PL_LD + 16 + l15] = __float2bfloat16(p1);
                Pl[wave][row * PL_LD + 32 + l15] = __float2bfloat16(p2);
                Pl[wave][row * PL_LD + 48 + l15] = __float2bfloat16(p3);
                float s2 = (p0 + p1) + (p2 + p3);
#pragma unroll
                for (int o = 1; o < 16; o <<= 1) s2 += __shfl_xor(s2, o);
                l_[r] += s2;
            }
            // PV (Pl same-wave write->read: LDS ops in-order per wave)
            short8 pf0 = *(const short8*)&Pl[wave][l15 * PL_LD + g * 8];
            short8 pf1 = *(const short8*)&Pl[wave][l15 * PL_LD + 32 + g * 8];
#pragma unroll
            for (int nt = 0; nt < 8; ++nt) {
                int d = nt * 16 + l15;
                int dsw = (d & 7) << 3;
                short8 vf0 = *(const short8*)&Vt[d * 64 + ((g * 8) ^ dsw)];
                short8 vf1 = *(const short8*)&Vt[d * 64 + ((32 + g * 8) ^ dsw)];
                acc[nt] = __builtin_amdgcn_mfma_f32_16x16x32_bf16(pf0, vf0, acc[nt], 0, 0, 0);
                acc[nt] = __builtin_amdgcn_mfma_f32_16x16x32_bf16(pf1, vf1, acc[nt], 0, 0, 0);
            }
            __syncthreads();   // Ks/Vt free to restage
        }
        // epilogue for this qt
        int qrow = qrow0 + g * 4;
#pragma unroll
        for (int nt = 0; nt < 8; ++nt) {
            int d = nt * 16 + l15;
#pragma unroll
            for (int r = 0; r < 4; ++r)
                y[(size_t)(b * SEQ + qrow + r) * D_MODEL + h * HD + d] =
                    __float2bfloat16(acc[nt][r] / l_[r]);
        }
    }
}

extern "C" void kernel_launch(void* const* d_in, const int* in_sizes, int n_in,
                              void* d_out, int out_size, void* d_ws, size_t ws_size,
                              hipStream_t stream) {
    const float* x  = (const float*)d_in[0];
    const float* wq = (const float*)d_in[1];
    const float* wk = (const float*)d_in[2];
    const float* wv = (const float*)d_in[3];
    const float* wo = (const float*)d_in[4];

    // ws (50.33MB proven): qkvb bf16 [4096][3072] @0 | ybb bf16 [4096][2048] | woT bf16 [2048][2048]
    // d_out (33.55MB scratch): xb bf16 @0 (16.78MB) + wqkvT bf16 (12.58MB) + trig (1.05MB)
    //   after gemm1: vT bf16 [1024][2048] @0 (4.19MB, over dead xb; trig still live? no—dead after gemm1)
    //   final: gemm2 writes fp32 output over all of d_out.
    bf16*   qkvb  = (bf16*)d_ws;
    bf16*   ybb   = (bf16*)d_ws + (size_t)NTOK * 3072;
    bf16*   woT   = (bf16*)d_ws + (size_t)NTOK * 3072 + (size_t)NTOK * D_MODEL;
    bf16*   xb    = (bf16*)d_out;
    bf16*   wqkvT = (bf16*)d_out + (size_t)NTOK * D_MODEL;
    float2* trig  = (float2*)((bf16*)d_out + (size_t)NTOK * D_MODEL + (size_t)QKV_N * D_MODEL);
    bf16*   vT    = (bf16*)d_out;      // over dead xb after gemm1
    float*  outf  = (float*)d_out;

    // phase 1: converts + trig table
    conv8<<<dim3(NTOK * D_MODEL / (256 * 8)), 256, 0, stream>>>(x, xb, NTOK * D_MODEL / 8);
    ct64<<<dim3(32, 32), 256, 0, stream>>>(wq, wqkvT, 2048, 2048);
    ct64<<<dim3(8, 32), 256, 0, stream>>>(wk, wqkvT + (size_t)2048 * 2048, 2048, 512);
    ct64<<<dim3(8, 32), 256, 0, stream>>>(wv, wqkvT + (size_t)2560 * 2048, 2048, 512);
    ct64<<<dim3(32, 32), 256, 0, stream>>>(wo, woT, 2048, 2048);
    trig_kernel<<<dim3(SEQ * 64 / 256), 256, 0, stream>>>(trig);

    // phase 2: QKV projection with fused RoPE -> qkvb (bf16, ws)
    gemm_bt<bf16, true><<<dim3(QKV_N / 128, NTOK / 128), 256, 0, stream>>>(
        xb, wqkvT, qkvb, NTOK, QKV_N, D_MODEL, trig);

    // phase 2.5: V^T (reads qkvb v-cols, writes vT over dead xb)
    vt64<<<dim3(8, 32, BATCH), 256, 0, stream>>>(qkvb, vT);

    // phase 3: attention -> ybb (ws)
    attn4<<<dim3(16, NHEADS, BATCH), 256, 0, stream>>>(qkvb, vT, ybb);

    // phase 4: out-projection -> fp32 directly into d_out (vT/trig dead)
    gemm_bt<float, false><<<dim3(D_MODEL / 128, NTOK / 128), 256, 0, stream>>>(
        ybb, woT, outf, NTOK, D_MODEL, D_MODEL, nullptr);
}

// Round 15
// 272.102 us; speedup vs baseline: 72.5936x; 1.0246x over previous
//
#include <hip/hip_runtime.h>
#include <hip/hip_bf16.h>
#include <stdint.h>

typedef __hip_bfloat16 bf16;
typedef __attribute__((ext_vector_type(8))) short short8;
typedef __attribute__((ext_vector_type(4))) float f32x4;

#define D_MODEL 2048
#define NHEADS 16
#define NKV 4
#define HD 128
#define BATCH 2
#define SEQ 2048
#define NTOK (BATCH*SEQ)
#define QKV_N 3072
#define QSCALE 0.08838834764831845f

// ---------------- trig table: [s][i] -> (cos, sin), double precision ----------------
__global__ __launch_bounds__(256) void trig_kernel(float2* __restrict__ tab) {
    int idx = blockIdx.x * 256 + threadIdx.x;       // < 2048*64
    int s = idx >> 6, i = idx & 63;
    double inv_freq = pow(10000.0, -(double)i / 64.0);
    double sn, cs;
    sincos((double)s * inv_freq, &sn, &cs);
    tab[idx] = make_float2((float)cs, (float)sn);
}

// ---------------- vectorized convert: fp32 -> bf16 (8 el/thread) ----------------
__global__ __launch_bounds__(256) void conv8(const float* __restrict__ in,
                                             bf16* __restrict__ out, int n8) {
    int idx = blockIdx.x * 256 + threadIdx.x;
    if (idx >= n8) return;
    const float4* p = (const float4*)(in + (size_t)idx * 8);
    float4 a = p[0], b = p[1];
    union { short8 v; bf16 e[8]; } u;
    u.e[0] = __float2bfloat16(a.x); u.e[1] = __float2bfloat16(a.y);
    u.e[2] = __float2bfloat16(a.z); u.e[3] = __float2bfloat16(a.w);
    u.e[4] = __float2bfloat16(b.x); u.e[5] = __float2bfloat16(b.y);
    u.e[6] = __float2bfloat16(b.z); u.e[7] = __float2bfloat16(b.w);
    *(short8*)(out + (size_t)idx * 8) = u.v;
}

// ------- convert-transpose: fp32 [K][N] -> bf16 [N][K]; TILE_LD=68 (272B rows, aligned) -------
#define TILE_LD 68
__global__ __launch_bounds__(256) void ct64(const float* __restrict__ in,
                                            bf16* __restrict__ out, int K, int N) {
    __shared__ float tile[64 * TILE_LD];
    int n0 = blockIdx.x * 64, k0 = blockIdx.y * 64;
    int t = threadIdx.x;
#pragma unroll
    for (int i = 0; i < 4; ++i) {
        int idx = t + 256 * i;
        int r = idx >> 4;
        int c4 = (idx & 15) * 4;
        *(float4*)&tile[r * TILE_LD + c4] = *(const float4*)(in + (size_t)(k0 + r) * N + n0 + c4);
    }
    __syncthreads();
#pragma unroll
    for (int i = 0; i < 2; ++i) {
        int idx = t + 256 * i;
        int n = idx >> 3;
        int kc = (idx & 7) * 8;
        union { short8 v; bf16 e[8]; } u;
#pragma unroll
        for (int j = 0; j < 8; ++j) u.e[j] = __float2bfloat16(tile[(kc + j) * TILE_LD + n]);
        *(short8*)(out + (size_t)(n0 + n) * K + k0 + kc) = u.v;
    }
}

// ---- V^T: qkvb v-cols [token][2560+vd] -> vT [(b*512+vd)][s] (bf16, 64x64 LDS tiles) ----
__global__ __launch_bounds__(256) void vt64(const bf16* __restrict__ qkvb,
                                            bf16* __restrict__ vT) {
    __shared__ bf16 tile[64 * 72];
    int vd0 = blockIdx.x * 64, s0 = blockIdx.y * 64, b = blockIdx.z;
    int t = threadIdx.x;
#pragma unroll
    for (int i = 0; i < 2; ++i) {
        int idx = t + 256 * i;
        int r = idx >> 3;
        int c8 = (idx & 7) * 8;
        *(int4*)&tile[r * 72 + c8] =
            *(const int4*)(qkvb + (size_t)(b * SEQ + s0 + r) * QKV_N + 2560 + vd0 + c8);
    }
    __syncthreads();
#pragma unroll
    for (int i = 0; i < 2; ++i) {
        int idx = t + 256 * i;
        int vd = idx >> 3;
        int s8 = (idx & 7) * 8;
        union { short8 v; bf16 e[8]; } u;
#pragma unroll
        for (int j = 0; j < 8; ++j) u.e[j] = tile[(s8 + j) * 72 + vd];
        *(short8*)(vT + (size_t)(b * 512 + vd0 + vd) * 2048 + s0 + s8) = u.v;
    }
}

// ------------- GEMM (m97 structure); fused-RoPE + q-prescale bf16 epilogue -------------
template <typename OutT, bool ROPE>
__global__ __launch_bounds__(256) void gemm_bt(const bf16* __restrict__ A,
                                               const bf16* __restrict__ Bt,
                                               OutT* __restrict__ C, int M, int N, int K,
                                               const float2* __restrict__ trig) {
    __shared__ bf16 As[128 * 32];
    __shared__ bf16 Bs[128 * 32];
    const int m0 = blockIdx.y * 128, n0 = blockIdx.x * 128;
    const int tid = threadIdx.x;
    const int wave = tid >> 6, lane = tid & 63;
    const int wr = wave >> 1, wc = wave & 1;
    const int l15 = lane & 15, g = lane >> 4;
    const int srow = lane >> 2;
    const int sk8 = (lane & 3) * 8;
    f32x4 acc[4][4] = {};

    for (int k0 = 0; k0 < K; k0 += 32) {
        __syncthreads();
#pragma unroll
        for (int i = 0; i < 2; ++i) {
            int chunk = wave * 2 + i;
            const bf16* ga = A + (size_t)(m0 + chunk * 16 + srow) * K + k0 + sk8;
            bf16* la = As + chunk * 512 + lane * 8;
            __builtin_amdgcn_global_load_lds((const __attribute__((address_space(1))) void*)ga,
                                             (__attribute__((address_space(3))) void*)la, 16, 0, 0);
            const bf16* gb = Bt + (size_t)(n0 + chunk * 16 + srow) * K + k0 + sk8;
            bf16* lb = Bs + chunk * 512 + lane * 8;
            __builtin_amdgcn_global_load_lds((const __attribute__((address_space(1))) void*)gb,
                                             (__attribute__((address_space(3))) void*)lb, 16, 0, 0);
        }
        __syncthreads();
        short8 af[4], bfr[4];
#pragma unroll
        for (int mi = 0; mi < 4; ++mi)
            af[mi] = *(const short8*)&As[(wr * 64 + mi * 16 + l15) * 32 + g * 8];
#pragma unroll
        for (int ni = 0; ni < 4; ++ni)
            bfr[ni] = *(const short8*)&Bs[(wc * 64 + ni * 16 + l15) * 32 + g * 8];
#pragma unroll
        for (int mi = 0; mi < 4; ++mi)
#pragma unroll
            for (int ni = 0; ni < 4; ++ni)
                acc[mi][ni] = __builtin_amdgcn_mfma_f32_16x16x32_bf16(af[mi], bfr[ni], acc[mi][ni], 0, 0, 0);
    }
#pragma unroll
    for (int mi = 0; mi < 4; ++mi)
#pragma unroll
        for (int ni = 0; ni < 4; ++ni) {
            int row = m0 + wr * 64 + mi * 16 + g * 4;
            int col = n0 + wc * 64 + ni * 16 + l15;
#pragma unroll
            for (int r = 0; r < 4; ++r) {
                float v = acc[mi][ni][r];
                if constexpr (ROPE) {
                    float partner = __shfl_xor(v, 1);   // pair lane (col^1)
                    if (col < 2560) {
                        int s = (row + r) & (SEQ - 1);
                        int i2 = (col & 127) >> 1;
                        float2 t = trig[s * 64 + i2];
                        v = (col & 1) ? (v * t.x + partner * t.y)
                                      : (v * t.x - partner * t.y);
                    }
                    if (col < 2048) v *= QSCALE;   // fold attention scale into q
                }
                if constexpr (__is_same(OutT, float))
                    C[(size_t)(row + r) * N + col] = v;
                else
                    C[(size_t)(row + r) * N + col] = __float2bfloat16(v);
            }
        }
}

// ---- MFMA flash attention v5: lean softmax (diag-only mask, hoisted l-reduce, prescaled q) ----
// grid (16, NHEADS, BATCH), 256 thr. Block bx handles qt = bx and 31-bx.
#define PL_LD 72
__global__ __launch_bounds__(256) void attn5(const bf16* __restrict__ qkv,
                                             const bf16* __restrict__ vT,
                                             bf16* __restrict__ y) {
    const int bx = blockIdx.x, h = blockIdx.y, b = blockIdx.z;
    const int kvh = h >> 2;
    const int tid = threadIdx.x, wave = tid >> 6, lane = tid & 63;
    const int l15 = lane & 15, g = lane >> 4;
    __shared__ bf16 Ks[64 * 128];
    __shared__ bf16 Vt[128 * 64];
    __shared__ bf16 Pl[4][16 * PL_LD];
    bf16* plw = Pl[0] + wave * 16 * PL_LD;

    for (int half = 0; half < 2; ++half) {
        const int qt = half ? (31 - bx) : bx;
        const int qrow0 = qt * 64 + wave * 16;
        short8 qf[4];
        {
            const bf16* qp = qkv + (size_t)(b * SEQ + qrow0 + l15) * QKV_N + h * HD + g * 8;
#pragma unroll
            for (int c = 0; c < 4; ++c) qf[c] = *(const short8*)(qp + c * 32);
        }
        f32x4 acc[8] = {};
        float m_[4], lsum[4];
#pragma unroll
        for (int r = 0; r < 4; ++r) { m_[r] = -3.0e38f; lsum[r] = 0.f; }

        const int diag_kv0 = qt * 64;
        for (int kv0 = 0; kv0 <= diag_kv0; kv0 += 64) {
            // stage K (64x128) + V^T (128x64) via global_load_lds, source pre-swizzled
#pragma unroll
            for (int i = 0; i < 4; ++i) {
                int cidx = tid + 256 * i;
                int key = cidx >> 4, j = cidx & 15;
                const bf16* gk = qkv + (size_t)(b * SEQ + kv0 + key) * QKV_N + D_MODEL
                               + kvh * HD + 8 * (j ^ (key & 7));
                __builtin_amdgcn_global_load_lds(
                    (const __attribute__((address_space(1))) void*)gk,
                    (__attribute__((address_space(3))) void*)(Ks + cidx * 8), 16, 0, 0);
                int d = cidx >> 3, j2 = cidx & 7;
                const bf16* gv = vT + (size_t)(b * 512 + kvh * HD + d) * 2048
                               + kv0 + 8 * (j2 ^ (d & 7));
                __builtin_amdgcn_global_load_lds(
                    (const __attribute__((address_space(1))) void*)gv,
                    (__attribute__((address_space(3))) void*)(Vt + cidx * 8), 16, 0, 0);
            }
            __syncthreads();

            // QK^T (q prescaled by QSCALE in gemm1)
            f32x4 sc[4];
#pragma unroll
            for (int ct = 0; ct < 4; ++ct) {
                sc[ct] = (f32x4){0.f, 0.f, 0.f, 0.f};
                int key = ct * 16 + l15;
                int ksw = (key & 7) << 3;
#pragma unroll
                for (int c = 0; c < 4; ++c) {
                    short8 kf = *(const short8*)&Ks[key * 128 + ((c * 32 + g * 8) ^ ksw)];
                    sc[ct] = __builtin_amdgcn_mfma_f32_16x16x32_bf16(qf[c], kf, sc[ct], 0, 0, 0);
                }
            }
            // causal mask: only the diagonal tile needs it
            if (kv0 == diag_kv0) {
                int qbase = qrow0 + g * 4;
#pragma unroll
                for (int ct = 0; ct < 4; ++ct) {
                    int key = kv0 + ct * 16 + l15;
#pragma unroll
                    for (int r = 0; r < 4; ++r)
                        if (key > qbase + r) sc[ct][r] = -3.0e38f;
                }
            }
            // online softmax: skip-rescale, per-lane partial l (reduced at epilogue)
#pragma unroll
            for (int r = 0; r < 4; ++r) {
                float mx = fmaxf(fmaxf(sc[0][r], sc[1][r]), fmaxf(sc[2][r], sc[3][r]));
#pragma unroll
                for (int o = 1; o < 16; o <<= 1) mx = fmaxf(mx, __shfl_xor(mx, o));
                if (mx > m_[r]) {
                    float alpha = __expf(m_[r] - mx);
                    m_[r] = mx;
                    lsum[r] *= alpha;
#pragma unroll
                    for (int nt = 0; nt < 8; ++nt) acc[nt][r] *= alpha;
                }
                float p0 = __expf(sc[0][r] - m_[r]);
                float p1 = __expf(sc[1][r] - m_[r]);
                float p2 = __expf(sc[2][r] - m_[r]);
                float p3 = __expf(sc[3][r] - m_[r]);
                int row = g * 4 + r;
                plw[row * PL_LD + l15]      = __float2bfloat16(p0);
                plw[row * PL_LD + 16 + l15] = __float2bfloat16(p1);
                plw[row * PL_LD + 32 + l15] = __float2bfloat16(p2);
                plw[row * PL_LD + 48 + l15] = __float2bfloat16(p3);
                lsum[r] += (p0 + p1) + (p2 + p3);
            }
            // PV
            short8 pf0 = *(const short8*)&plw[l15 * PL_LD + g * 8];
            short8 pf1 = *(const short8*)&plw[l15 * PL_LD + 32 + g * 8];
#pragma unroll
            for (int nt = 0; nt < 8; ++nt) {
                int d = nt * 16 + l15;
                int dsw = (d & 7) << 3;
                short8 vf0 = *(const short8*)&Vt[d * 64 + ((g * 8) ^ dsw)];
                short8 vf1 = *(const short8*)&Vt[d * 64 + ((32 + g * 8) ^ dsw)];
                acc[nt] = __builtin_amdgcn_mfma_f32_16x16x32_bf16(pf0, vf0, acc[nt], 0, 0, 0);
                acc[nt] = __builtin_amdgcn_mfma_f32_16x16x32_bf16(pf1, vf1, acc[nt], 0, 0, 0);
            }
            __syncthreads();   // Ks/Vt free to restage
        }
        // epilogue: reduce per-lane l partials, write y
        float linv[4];
#pragma unroll
        for (int r = 0; r < 4; ++r) {
            float ls = lsum[r];
#pragma unroll
            for (int o = 1; o < 16; o <<= 1) ls += __shfl_xor(ls, o);
            linv[r] = 1.0f / ls;
        }
        int qrow = qrow0 + g * 4;
#pragma unroll
        for (int nt = 0; nt < 8; ++nt) {
            int d = nt * 16 + l15;
#pragma unroll
            for (int r = 0; r < 4; ++r)
                y[(size_t)(b * SEQ + qrow + r) * D_MODEL + h * HD + d] =
                    __float2bfloat16(acc[nt][r] * linv[r]);
        }
    }
}

extern "C" void kernel_launch(void* const* d_in, const int* in_sizes, int n_in,
                              void* d_out, int out_size, void* d_ws, size_t ws_size,
                              hipStream_t stream) {
    const float* x  = (const float*)d_in[0];
    const float* wq = (const float*)d_in[1];
    const float* wk = (const float*)d_in[2];
    const float* wv = (const float*)d_in[3];
    const float* wo = (const float*)d_in[4];

    // ws (50.33MB proven): qkvb bf16 [4096][3072] @0 | ybb bf16 [4096][2048] | woT bf16 [2048][2048]
    // d_out (33.55MB scratch): xb bf16 @0 + wqkvT bf16 + trig; after gemm1: vT over dead xb;
    //   final: gemm2 writes fp32 output over all of d_out.
    bf16*   qkvb  = (bf16*)d_ws;
    bf16*   ybb   = (bf16*)d_ws + (size_t)NTOK * 3072;
    bf16*   woT   = (bf16*)d_ws + (size_t)NTOK * 3072 + (size_t)NTOK * D_MODEL;
    bf16*   xb    = (bf16*)d_out;
    bf16*   wqkvT = (bf16*)d_out + (size_t)NTOK * D_MODEL;
    float2* trig  = (float2*)((bf16*)d_out + (size_t)NTOK * D_MODEL + (size_t)QKV_N * D_MODEL);
    bf16*   vT    = (bf16*)d_out;
    float*  outf  = (float*)d_out;

    // phase 1: converts + trig table
    conv8<<<dim3(NTOK * D_MODEL / (256 * 8)), 256, 0, stream>>>(x, xb, NTOK * D_MODEL / 8);
    ct64<<<dim3(32, 32), 256, 0, stream>>>(wq, wqkvT, 2048, 2048);
    ct64<<<dim3(8, 32), 256, 0, stream>>>(wk, wqkvT + (size_t)2048 * 2048, 2048, 512);
    ct64<<<dim3(8, 32), 256, 0, stream>>>(wv, wqkvT + (size_t)2560 * 2048, 2048, 512);
    ct64<<<dim3(32, 32), 256, 0, stream>>>(wo, woT, 2048, 2048);
    trig_kernel<<<dim3(SEQ * 64 / 256), 256, 0, stream>>>(trig);

    // phase 2: QKV projection with fused RoPE + q-prescale -> qkvb (bf16, ws)
    gemm_bt<bf16, true><<<dim3(QKV_N / 128, NTOK / 128), 256, 0, stream>>>(
        xb, wqkvT, qkvb, NTOK, QKV_N, D_MODEL, trig);

    // phase 2.5: V^T (over dead xb)
    vt64<<<dim3(8, 32, BATCH), 256, 0, stream>>>(qkvb, vT);

    // phase 3: attention -> ybb (ws)
    attn5<<<dim3(16, NHEADS, BATCH), 256, 0, stream>>>(qkvb, vT, ybb);

    // phase 4: out-projection -> fp32 directly into d_out
    gemm_bt<float, false><<<dim3(D_MODEL / 128, NTOK / 128), 256, 0, stream>>>(
        ybb, woT, outf, NTOK, D_MODEL, D_MODEL, nullptr);
}